// Round 6
// baseline (689.083 us; speedup 1.0000x reference)
//
#include <hip/hip_runtime.h>
#include <math.h>

#define NEG_SLOPE 0.2f

typedef _Float16 half2v __attribute__((ext_vector_type(2)));
typedef _Float16 half8 __attribute__((ext_vector_type(8)));
typedef float float4v __attribute__((ext_vector_type(4)));
typedef float float2v __attribute__((ext_vector_type(2)));

__device__ __forceinline__ float lrelu(float x) { return x > 0.f ? x : NEG_SLOPE * x; }

__device__ __forceinline__ float sel4(const float4 v, int h) {
  float r = v.x;
  r = (h == 1) ? v.y : r;
  r = (h == 2) ? v.z : r;
  r = (h == 3) ? v.w : r;
  return r;
}

__device__ __forceinline__ unsigned char f32_to_fp8(float a) {
  int v = __builtin_amdgcn_cvt_pk_fp8_f32(a, 0.f, 0, false);
  return (unsigned char)(v & 0xff);
}

__device__ __forceinline__ void acc_fp8x8(float* acc, uint2 d, float ez) {
  float2v c0 = __builtin_amdgcn_cvt_pk_f32_fp8((int)d.x, false);
  float2v c1 = __builtin_amdgcn_cvt_pk_f32_fp8((int)d.x, true);
  float2v c2 = __builtin_amdgcn_cvt_pk_f32_fp8((int)d.y, false);
  float2v c3 = __builtin_amdgcn_cvt_pk_f32_fp8((int)d.y, true);
  acc[0] += ez * c0.x; acc[1] += ez * c0.y;
  acc[2] += ez * c1.x; acc[3] += ez * c1.y;
  acc[4] += ez * c2.x; acc[5] += ez * c2.y;
  acc[6] += ez * c3.x; acc[7] += ez * c3.y;
}

// ---------------- CSR build ----------------

__global__ void k_hist(const int* __restrict__ dst, int* __restrict__ cnt, int E) {
  int i = blockIdx.x * blockDim.x + threadIdx.x;
  if (i < E) atomicAdd(&cnt[dst[i]], 1);
}

__global__ __launch_bounds__(256) void k_offsets(const int* __restrict__ cnt,
                                                 int* __restrict__ row_start,
                                                 int* __restrict__ gcount, int N) {
  __shared__ int s[256];
  __shared__ int base;
  int tid = threadIdx.x;
  int i = blockIdx.x * 256 + tid;
  int c = (i < N) ? cnt[i] : 0;
  s[tid] = c;
  __syncthreads();
  for (int off = 1; off < 256; off <<= 1) {
    int v = 0;
    if (tid >= off) v = s[tid - off];
    __syncthreads();
    if (tid >= off) s[tid] += v;
    __syncthreads();
  }
  if (tid == 255) base = atomicAdd(gcount, s[255]);
  __syncthreads();
  if (i < N) row_start[i] = base + s[tid] - c;
}

__global__ void k_scatter(const int* __restrict__ src, const int* __restrict__ dst,
                          const int* __restrict__ row_start, int* __restrict__ fill,
                          int* __restrict__ srcs, int E) {
  int i = blockIdx.x * blockDim.x + threadIdx.x;
  if (i < E) {
    int d = dst[i];
    int p = row_start[d] + atomicAdd(&fill[d], 1);
    srcs[p] = src[i];
  }
}

// ---------------- fused prep: wlr0/1/2 + Wt0/1/2 ----------------
__device__ __forceinline__ void wlr_one(const float* Ws, const float* Wd,
                                        const float* al, const float* ar,
                                        float* wlr, int K, int Dh, int i) {
  int M = 4 * Dh;
  int k = i >> 2, h = i & 3;
  float sl = 0.f, sr = 0.f;
  for (int d = 0; d < Dh; d++) {
    sl += Ws[(size_t)k * M + h * Dh + d] * al[h * Dh + d];
    sr += Wd[(size_t)k * M + h * Dh + d] * ar[h * Dh + d];
  }
  wlr[k * 8 + h] = sl;
  wlr[k * 8 + 4 + h] = sr;
}

__global__ __launch_bounds__(256) void k_prep(
    const float* __restrict__ W0s, const float* __restrict__ W0d,
    const float* __restrict__ a0l, const float* __restrict__ a0r,
    const float* __restrict__ W1s, const float* __restrict__ W1d,
    const float* __restrict__ a1l, const float* __restrict__ a1r,
    const float* __restrict__ W2s, const float* __restrict__ W2d,
    const float* __restrict__ a2l, const float* __restrict__ a2r,
    float* __restrict__ wlr0, float* __restrict__ wlr1, float* __restrict__ wlr2,
    _Float16* __restrict__ Wt0, _Float16* __restrict__ Wt1, _Float16* __restrict__ Wt2) {
  int i = blockIdx.x * 256 + threadIdx.x;
  if (i < 1024) {
    wlr_one(W0s, W0d, a0l, a0r, wlr0, 256, 32, i);
  } else if (i < 1536) {
    wlr_one(W1s, W1d, a1l, a1r, wlr1, 128, 32, i - 1024);
  } else if (i < 2048) {
    wlr_one(W2s, W2d, a2l, a2r, wlr2, 128, 47, i - 1536);
  } else if (i < 2048 + 32768) {
    int j = i - 2048;                 // Wt0[128][256]
    int m = j >> 8, k = j & 255;
    Wt0[j] = (_Float16)W0s[(size_t)k * 128 + m];
  } else if (i < 2048 + 32768 + 16384) {
    int j = i - (2048 + 32768);       // Wt1[128][128]
    int m = j >> 7, k = j & 127;
    Wt1[j] = (_Float16)W1s[(size_t)k * 128 + m];
  } else if (i < 2048 + 32768 + 16384 + 24576) {
    int j = i - (2048 + 32768 + 16384);  // Wt2[192][128], head-padded rows 48*h+c
    int r = j >> 7, k = j & 127;
    int h = r / 48, c = r % 48;
    float v = (c < 47) ? W2s[(size_t)k * 188 + 47 * h + c] : 0.f;
    Wt2[j] = (_Float16)v;
  }
}

// ---------------- MFMA fp16 GEMM + fused el/er; C stored fp8 ----------------
template <int BN, typename AT>
__global__ __launch_bounds__(256) void k_gemm_mfma(const AT* __restrict__ A,
                                                   const _Float16* __restrict__ Bt,
                                                   const float* __restrict__ wlr,
                                                   unsigned char* __restrict__ C,
                                                   float* __restrict__ el,
                                                   float* __restrict__ er, int N, int K) {
  constexpr int NT = BN / 64;                 // n-tiles per wave (2 or 3)
  constexpr int ASZ = 4 * 64 * 8;             // 2048 fp16
  constexpr int BSZ = (BN / 16) * 64 * 8;     // 4096 or 6144 fp16
  constexpr int SSZ = ASZ + BSZ;
  __shared__ __align__(16) _Float16 smem[SSZ];
  __shared__ float swlr[2048];                // K*8 <= 2048; reused for eler reduction
  _Float16* As = smem;
  _Float16* Bs = smem + ASZ;

  const int tid = threadIdx.x;
  const int lane = tid & 63;
  const int w = tid >> 6;
  const int row0 = blockIdx.x * 64;

  for (int i = tid; i < K * 8; i += 256) swlr[i] = wlr[i];
  __syncthreads();

  float4v acc[4][NT];
#pragma unroll
  for (int i = 0; i < 4; i++)
#pragma unroll
    for (int j = 0; j < NT; j++) acc[i][j] = (float4v){0.f, 0.f, 0.f, 0.f};
  float p[8] = {0, 0, 0, 0, 0, 0, 0, 0};

  const int ar_ = tid >> 2, aq = tid & 3;
  for (int k0 = 0; k0 < K; k0 += 32) {
    {
      int gr = row0 + ar_;
      float a8[8];
      if (gr < N) {
        if constexpr (sizeof(AT) == 4) {
          const float4* pp = (const float4*)&A[(size_t)gr * K + k0 + aq * 8];
          float4 u0 = pp[0], u1 = pp[1];
          a8[0] = u0.x; a8[1] = u0.y; a8[2] = u0.z; a8[3] = u0.w;
          a8[4] = u1.x; a8[5] = u1.y; a8[6] = u1.z; a8[7] = u1.w;
        } else {
          half8 hv = *(const half8*)&A[(size_t)gr * K + k0 + aq * 8];
#pragma unroll
          for (int j = 0; j < 8; j++) a8[j] = (float)hv[j];
        }
      } else {
#pragma unroll
        for (int j = 0; j < 8; j++) a8[j] = 0.f;
      }
      half8 v;
#pragma unroll
      for (int j = 0; j < 8; j++) v[j] = (_Float16)a8[j];
      *(half8*)&As[(size_t)(((ar_ >> 4) * 64) + (ar_ & 15) + 16 * aq) * 8] = v;
#pragma unroll
      for (int j = 0; j < 8; j++) {
        const float av = a8[j];
        const float* wp = &swlr[(k0 + aq * 8 + j) * 8];
        float4 w0 = *(const float4*)wp;
        float4 w1 = *(const float4*)(wp + 4);
        p[0] += av * w0.x; p[1] += av * w0.y; p[2] += av * w0.z; p[3] += av * w0.w;
        p[4] += av * w1.x; p[5] += av * w1.y; p[6] += av * w1.z; p[7] += av * w1.w;
      }
    }
#pragma unroll
    for (int i = 0; i < NT; i++) {
      int idx = tid + i * 256;
      int n = idx >> 2, q = idx & 3;
      half8 v = *(const half8*)&Bt[(size_t)n * K + k0 + q * 8];
      *(half8*)&Bs[(size_t)((n >> 4) * 64 + (n & 15) + 16 * q) * 8] = v;
    }
    __syncthreads();
    half8 af[4];
#pragma unroll
    for (int mt = 0; mt < 4; mt++) af[mt] = *(half8*)&As[(size_t)(mt * 64 + lane) * 8];
#pragma unroll
    for (int nt = 0; nt < NT; nt++) {
      half8 bf = *(half8*)&Bs[(size_t)((w * NT + nt) * 64 + lane) * 8];
#pragma unroll
      for (int mt = 0; mt < 4; mt++)
        acc[mt][nt] = __builtin_amdgcn_mfma_f32_16x16x32_f16(af[mt], bf, acc[mt][nt], 0, 0, 0);
    }
    __syncthreads();
  }

#pragma unroll
  for (int j = 0; j < 8; j++) swlr[(ar_ * 4 + aq) * 8 + j] = p[j];

  unsigned char* cs = (unsigned char*)smem;
  const int quad = lane >> 4;
#pragma unroll
  for (int mt = 0; mt < 4; mt++)
#pragma unroll
    for (int nt = 0; nt < NT; nt++)
#pragma unroll
      for (int reg = 0; reg < 4; reg++) {
        int r = mt * 16 + quad * 4 + reg;
        int cc = (w * NT + nt) * 16 + (lane & 15);
        cs[r * BN + cc] = f32_to_fp8(acc[mt][nt][reg]);
      }
  __syncthreads();
  if (tid < 64) {
    int gr = row0 + tid;
    if (gr < N) {
      float e[8];
#pragma unroll
      for (int j = 0; j < 8; j++)
        e[j] = swlr[(tid * 4 + 0) * 8 + j] + swlr[(tid * 4 + 1) * 8 + j] +
               swlr[(tid * 4 + 2) * 8 + j] + swlr[(tid * 4 + 3) * 8 + j];
      *(float4*)&el[(size_t)gr * 4] = make_float4(e[0], e[1], e[2], e[3]);
      *(float4*)&er[(size_t)gr * 4] = make_float4(e[4], e[5], e[6], e[7]);
    }
  }
  constexpr int PER = (64 * BN) / (256 * 16);
  const uint4* s4 = (const uint4*)cs;
#pragma unroll
  for (int i = 0; i < PER; i++) {
    int idx = tid + i * 256;
    int r = idx / (BN / 16), c16 = idx % (BN / 16);
    int gr = row0 + r;
    if (gr < N) *(uint4*)&C[(size_t)gr * BN + c16 * 16] = s4[idx];
  }
}

// ---------------- edge aggregation, layers 0/1 (F fp8, stride 128) ----------------
// 4 groups of 16 lanes; software-pipelined 4-deep: chunk padded to multiple of 16
// with zero-ez dummy slots so 4 independent gathers are in flight per lane.
__global__ __launch_bounds__(256) void k_edge_mid(
    const unsigned char* __restrict__ F, const float* __restrict__ el,
    const float* __restrict__ er, const int* __restrict__ row_start,
    const int* __restrict__ cnt, const int* __restrict__ srcs,
    const float* __restrict__ bias, _Float16* __restrict__ hout, int N) {
  __shared__ float sEz[4][64][4];
  __shared__ int sU[4][64];
  int lane = threadIdx.x & 63;
  int w = threadIdx.x >> 6;
  int v = blockIdx.x * 4 + w;
  if (v >= N) return;
  int start = row_start[v], deg = cnt[v];
  float4 erv = *(const float4*)&er[(size_t)v * 4];
  const int g = lane >> 4;
  const int fl = lane & 15;
  const int h = fl >> 2;
  float acc[8] = {0, 0, 0, 0, 0, 0, 0, 0};
  float4 lsum = make_float4(0.f, 0.f, 0.f, 0.f);

  for (int c = 0; c < deg; c += 64) {
    int take = min(64, deg - c);
    int tp = (take + 15) & ~15;
    {
      int u = 0;
      float4 ez = make_float4(0.f, 0.f, 0.f, 0.f);
      if (lane < take) {
        u = srcs[start + c + lane];
        float4 e = *(const float4*)&el[(size_t)u * 4];
        ez.x = __expf(lrelu(e.x + erv.x));
        ez.y = __expf(lrelu(e.y + erv.y));
        ez.z = __expf(lrelu(e.z + erv.z));
        ez.w = __expf(lrelu(e.w + erv.w));
        lsum.x += ez.x; lsum.y += ez.y; lsum.z += ez.z; lsum.w += ez.w;
      }
      sU[w][lane] = u;  // dummy slots: u=0, ez=0 (harmless)
      *(float4*)&sEz[w][lane][0] = ez;
    }
    // wave-private LDS region: same-wave DS ops are in-order; no barrier.
    for (int kk = g; kk < tp; kk += 16) {
      int u0 = sU[w][kk];
      int u1 = sU[w][kk + 4];
      int u2 = sU[w][kk + 8];
      int u3 = sU[w][kk + 12];
      float e0 = sEz[w][kk][h];
      float e1 = sEz[w][kk + 4][h];
      float e2 = sEz[w][kk + 8][h];
      float e3 = sEz[w][kk + 12][h];
      uint2 d0 = *(const uint2*)&F[(size_t)u0 * 128 + 8 * fl];
      uint2 d1 = *(const uint2*)&F[(size_t)u1 * 128 + 8 * fl];
      uint2 d2 = *(const uint2*)&F[(size_t)u2 * 128 + 8 * fl];
      uint2 d3 = *(const uint2*)&F[(size_t)u3 * 128 + 8 * fl];
      acc_fp8x8(acc, d0, e0);
      acc_fp8x8(acc, d1, e1);
      acc_fp8x8(acc, d2, e2);
      acc_fp8x8(acc, d3, e3);
    }
  }
#pragma unroll
  for (int j = 0; j < 8; j++) {
    acc[j] += __shfl_xor(acc[j], 16);
    acc[j] += __shfl_xor(acc[j], 32);
  }
#pragma unroll
  for (int msk = 1; msk < 64; msk <<= 1) {
    lsum.x += __shfl_xor(lsum.x, msk);
    lsum.y += __shfl_xor(lsum.y, msk);
    lsum.z += __shfl_xor(lsum.z, msk);
    lsum.w += __shfl_xor(lsum.w, msk);
  }
  if (g == 0) {
    float inv = (deg > 0) ? 1.f / sel4(lsum, h) : 0.f;
    const float4* bp = (const float4*)&bias[8 * fl];
    float4 b0v = bp[0], b1v = bp[1];
    float bb[8] = {b0v.x, b0v.y, b0v.z, b0v.w, b1v.x, b1v.y, b1v.z, b1v.w};
    half8 o;
#pragma unroll
    for (int j = 0; j < 8; j++) o[j] = (_Float16)fmaxf(fmaf(acc[j], inv, bb[j]), 0.f);
    *(half8*)&hout[(size_t)v * 128 + 8 * fl] = o;
  }
}

// ---------------- edge aggregation, layer 2 (F fp8, head-padded 4x48, stride 192) ----------------
// 2 parity halves of 24 active lanes; 4-deep pipeline over parity stride 2.
__global__ __launch_bounds__(256) void k_edge_final(
    const unsigned char* __restrict__ F, const float* __restrict__ el,
    const float* __restrict__ er, const int* __restrict__ row_start,
    const int* __restrict__ cnt, const int* __restrict__ srcs,
    const float* __restrict__ b2, float* __restrict__ out, int N) {
  __shared__ float sEz[4][64][4];
  __shared__ int sU[4][64];
  __shared__ float red[4][192];
  int lane = threadIdx.x & 63;
  int w = threadIdx.x >> 6;
  int v = blockIdx.x * 4 + w;
  if (v >= N) return;
  int start = row_start[v], deg = cnt[v];
  float4 erv = *(const float4*)&er[(size_t)v * 4];
  const int sub = lane >> 5;
  const int l24 = lane & 31;
  const bool act = l24 < 24;
  const int h = l24 / 6;
  const int j6 = l24 % 6;
  const int foff = 48 * h + 8 * j6;
  float acc[8] = {0, 0, 0, 0, 0, 0, 0, 0};
  float4 lsum = make_float4(0.f, 0.f, 0.f, 0.f);

  for (int c = 0; c < deg; c += 64) {
    int take = min(64, deg - c);
    int tp = (take + 7) & ~7;
    {
      int u = 0;
      float4 ez = make_float4(0.f, 0.f, 0.f, 0.f);
      if (lane < take) {
        u = srcs[start + c + lane];
        float4 e = *(const float4*)&el[(size_t)u * 4];
        ez.x = __expf(lrelu(e.x + erv.x));
        ez.y = __expf(lrelu(e.y + erv.y));
        ez.z = __expf(lrelu(e.z + erv.z));
        ez.w = __expf(lrelu(e.w + erv.w));
        lsum.x += ez.x; lsum.y += ez.y; lsum.z += ez.z; lsum.w += ez.w;
      }
      sU[w][lane] = u;
      *(float4*)&sEz[w][lane][0] = ez;
    }
    if (act) {
      for (int kk = sub; kk < tp; kk += 8) {
        int u0 = sU[w][kk];
        int u1 = sU[w][kk + 2];
        int u2 = sU[w][kk + 4];
        int u3 = sU[w][kk + 6];
        float e0 = sEz[w][kk][h];
        float e1 = sEz[w][kk + 2][h];
        float e2 = sEz[w][kk + 4][h];
        float e3 = sEz[w][kk + 6][h];
        uint2 d0 = *(const uint2*)&F[(size_t)u0 * 192 + foff];
        uint2 d1 = *(const uint2*)&F[(size_t)u1 * 192 + foff];
        uint2 d2 = *(const uint2*)&F[(size_t)u2 * 192 + foff];
        uint2 d3 = *(const uint2*)&F[(size_t)u3 * 192 + foff];
        acc_fp8x8(acc, d0, e0);
        acc_fp8x8(acc, d1, e1);
        acc_fp8x8(acc, d2, e2);
        acc_fp8x8(acc, d3, e3);
      }
    }
  }
#pragma unroll
  for (int j = 0; j < 8; j++) acc[j] += __shfl_xor(acc[j], 32);
#pragma unroll
  for (int msk = 1; msk < 64; msk <<= 1) {
    lsum.x += __shfl_xor(lsum.x, msk);
    lsum.y += __shfl_xor(lsum.y, msk);
    lsum.z += __shfl_xor(lsum.z, msk);
    lsum.w += __shfl_xor(lsum.w, msk);
  }
  if (act && sub == 0) {
    float inv = (deg > 0) ? 1.f / sel4(lsum, h) : 0.f;
#pragma unroll
    for (int j = 0; j < 8; j++) {
      int cc = 8 * j6 + j;
      float bv = (cc < 47) ? b2[47 * h + cc] : 0.f;
      red[w][foff + j] = fmaf(acc[j], inv, bv);
    }
  }
  __syncthreads();
  float g = -INFINITY;
  if (lane < 47)
    g = 0.25f * (red[w][lane] + red[w][lane + 48] + red[w][lane + 96] + red[w][lane + 144]);
  float gm = g;
#pragma unroll
  for (int msk = 1; msk < 64; msk <<= 1) gm = fmaxf(gm, __shfl_xor(gm, msk));
  float ex = (lane < 47) ? __expf(g - gm) : 0.f;
  float s = ex;
#pragma unroll
  for (int msk = 1; msk < 64; msk <<= 1) s += __shfl_xor(s, msk);
  if (lane < 47) out[(size_t)v * 47 + lane] = g - gm - __logf(s);
}

// ---------------- launch ----------------
extern "C" void kernel_launch(void* const* d_in, const int* in_sizes, int n_in,
                              void* d_out, int out_size, void* d_ws, size_t ws_size,
                              hipStream_t stream) {
  const float* x = (const float*)d_in[0];
  const int* src = (const int*)d_in[1];
  const int* dst = (const int*)d_in[2];
  const float* W0s = (const float*)d_in[3];
  const float* W0d = (const float*)d_in[4];
  const float* a0l = (const float*)d_in[5];
  const float* a0r = (const float*)d_in[6];
  const float* b0 = (const float*)d_in[7];
  const float* W1s = (const float*)d_in[8];
  const float* W1d = (const float*)d_in[9];
  const float* a1l = (const float*)d_in[10];
  const float* a1r = (const float*)d_in[11];
  const float* b1 = (const float*)d_in[12];
  const float* W2s = (const float*)d_in[13];
  const float* W2d = (const float*)d_in[14];
  const float* a2l = (const float*)d_in[15];
  const float* a2r = (const float*)d_in[16];
  const float* b2 = (const float*)d_in[17];
  float* out = (float*)d_out;

  const int N = in_sizes[0] / 256;  // 100000
  const int E = in_sizes[1];        // 1600000

  char* w = (char*)d_ws;
  size_t off = 0;
  auto alloc = [&](size_t bytes) -> void* {
    void* p = w + off;
    off += (bytes + 255) & ~(size_t)255;
    return p;
  };
  int* gcount = (int*)alloc(4);
  int* cnt = (int*)alloc((size_t)N * 4);
  int* fill = (int*)alloc((size_t)N * 4);
  size_t zbytes = off;  // zero gcount+cnt+fill
  int* row_start = (int*)alloc((size_t)N * 4);
  int* srcs = (int*)alloc((size_t)E * 4);
  float* wlr0 = (float*)alloc(256 * 8 * 4);
  float* wlr1 = (float*)alloc(128 * 8 * 4);
  float* wlr2 = (float*)alloc(128 * 8 * 4);
  _Float16* Wt0 = (_Float16*)alloc(128 * 256 * 2);
  _Float16* Wt1 = (_Float16*)alloc(128 * 128 * 2);
  _Float16* Wt2 = (_Float16*)alloc(192 * 128 * 2);
  float* el = (float*)alloc((size_t)N * 4 * 4);
  float* er = (float*)alloc((size_t)N * 4 * 4);
  unsigned char* F = (unsigned char*)alloc((size_t)N * 192);
  _Float16* Ha = (_Float16*)alloc((size_t)N * 128 * 2);
  _Float16* Hc = (_Float16*)alloc((size_t)N * 128 * 2);
  (void)ws_size;

  hipMemsetAsync(d_ws, 0, zbytes, stream);
  k_hist<<<(E + 255) / 256, 256, 0, stream>>>(dst, cnt, E);
  k_offsets<<<(N + 255) / 256, 256, 0, stream>>>(cnt, row_start, gcount, N);
  k_scatter<<<(E + 255) / 256, 256, 0, stream>>>(src, dst, row_start, fill, srcs, E);
  k_prep<<<(75776 + 255) / 256, 256, 0, stream>>>(W0s, W0d, a0l, a0r, W1s, W1d, a1l, a1r,
                                                  W2s, W2d, a2l, a2r, wlr0, wlr1, wlr2,
                                                  Wt0, Wt1, Wt2);

  int gemm_grid = (N + 63) / 64;
  int node_grid = (N + 3) / 4;

  // layer 0: K=256, fp32 A (x)
  k_gemm_mfma<128, float><<<gemm_grid, 256, 0, stream>>>(x, Wt0, wlr0, F, el, er, N, 256);
  k_edge_mid<<<node_grid, 256, 0, stream>>>(F, el, er, row_start, cnt, srcs, b0, Ha, N);

  // layer 1: K=128, fp16 A
  k_gemm_mfma<128, _Float16><<<gemm_grid, 256, 0, stream>>>(Ha, Wt1, wlr1, F, el, er, N, 128);
  k_edge_mid<<<node_grid, 256, 0, stream>>>(F, el, er, row_start, cnt, srcs, b1, Hc, N);

  // layer 2: K=128, M=192 head-padded (4 x 48, col 47 of each head zero)
  k_gemm_mfma<192, _Float16><<<gemm_grid, 256, 0, stream>>>(Hc, Wt2, wlr2, F, el, er, N, 128);
  k_edge_final<<<node_grid, 256, 0, stream>>>(F, el, er, row_start, cnt, srcs, b2, out, N);
}